// Round 1
// baseline (818.731 us; speedup 1.0000x reference)
//
#include <hip/hip_runtime.h>
#include <math.h>

// Problem dims
constexpr int B_   = 4;
constexpr int L_   = 1024;
constexpr int DIN_ = 64;
constexpr int DOUT_= 10;
constexpr int D_   = 512;
constexpr int N_   = 16;
constexpr int R_   = 32;
constexpr int RN_  = 64;          // R + 2N
constexpr int M_   = B_ * L_;     // 4096 rows (b,l) flattened

// Intermediates as device globals (avoids relying on ws_size; all fully
// overwritten each call, so re-poisoning of d_ws/d_out is irrelevant).
__device__ float  g_h   [M_ * D_];    // hidden after in-proj / after mix1
__device__ float  g_h2  [M_ * D_];    // hidden after mix1 (layer-2 input/residual)
__device__ float  g_y   [M_ * D_];    // raw mamba output (pre-GELU)
__device__ float  g_xdbl[M_ * RN_];   // [dt(32) | B(16) | C(16)] per row
__device__ float2 g_dc  [M_ * D_];    // (delta, delta*h) per (row,d)

__device__ __forceinline__ float gelu_f(float x) {
  return 0.5f * x * (1.0f + erff(x * 0.7071067811865475f));
}
__device__ __forceinline__ float softplus_f(float x) {
  // matches jax.nn.softplus: max(x,0) + log1p(exp(-|x|))
  return fmaxf(x, 0.0f) + log1pf(__expf(-fabsf(x)));
}

// ---------------------------------------------------------------------------
// Generic fp32 tiled GEMM:  out[m,n] = sum_k A[m,k] * Bt[n,k]  (+ epilogue)
// BM=BN=64, BK=16, 256 threads, 4x4 per thread.
// EPI: 0 = +bias, store
//      1 = +bias +res, store
//      2 = delta epilogue: delta=softplus(acc+bias); store (delta, delta*H)
//      3 = plain store
// ---------------------------------------------------------------------------
template<int K, int LDA, int NN, bool GELU_A, int EPI>
__device__ __forceinline__ void gemm_dev(const float* __restrict__ A,
                                         const float* __restrict__ Bt,
                                         const float* __restrict__ bias,
                                         const float* __restrict__ res,
                                         float* __restrict__ out) {
  __shared__ float As[16][68];
  __shared__ float Bs[16][68];
  const int tid = threadIdx.x;
  const int tx = tid & 15;        // n quad
  const int ty = tid >> 4;        // m quad
  const int lm = tid >> 2;        // load row 0..63
  const int lk = (tid & 3) << 2;  // load k {0,4,8,12}
  constexpr int NB = NN / 64;
  const int m0 = (blockIdx.x / NB) * 64;
  const int n0 = (blockIdx.x % NB) * 64;

  float acc[4][4] = {};
  for (int k0 = 0; k0 < K; k0 += 16) {
    float4 av = *(const float4*)&A[(size_t)(m0 + lm) * LDA + k0 + lk];
    if (GELU_A) {
      av.x = gelu_f(av.x); av.y = gelu_f(av.y);
      av.z = gelu_f(av.z); av.w = gelu_f(av.w);
    }
    float4 bv = *(const float4*)&Bt[(size_t)(n0 + lm) * K + k0 + lk];
    As[lk + 0][lm] = av.x; As[lk + 1][lm] = av.y;
    As[lk + 2][lm] = av.z; As[lk + 3][lm] = av.w;
    Bs[lk + 0][lm] = bv.x; Bs[lk + 1][lm] = bv.y;
    Bs[lk + 2][lm] = bv.z; Bs[lk + 3][lm] = bv.w;
    __syncthreads();
#pragma unroll
    for (int k = 0; k < 16; ++k) {
      float4 a = *(const float4*)&As[k][ty << 2];
      float4 b = *(const float4*)&Bs[k][tx << 2];
      float aa[4] = {a.x, a.y, a.z, a.w};
      float bb[4] = {b.x, b.y, b.z, b.w};
#pragma unroll
      for (int i = 0; i < 4; ++i)
#pragma unroll
        for (int j = 0; j < 4; ++j)
          acc[i][j] = fmaf(aa[i], bb[j], acc[i][j]);
    }
    __syncthreads();
  }

  const int nb = n0 + (tx << 2);
  float b4[4] = {0.f, 0.f, 0.f, 0.f};
  if constexpr (EPI != 3) {
    float4 t = *(const float4*)&bias[nb];
    b4[0] = t.x; b4[1] = t.y; b4[2] = t.z; b4[3] = t.w;
  }
#pragma unroll
  for (int i = 0; i < 4; ++i) {
    const int m = m0 + (ty << 2) + i;
    if constexpr (EPI == 2) {
      const float* hrow = &res[(size_t)m * NN];
      float2* o2 = (float2*)out;
#pragma unroll
      for (int j = 0; j < 4; ++j) {
        float delta = softplus_f(acc[i][j] + b4[j]);
        float c = delta * hrow[nb + j];
        o2[(size_t)m * NN + nb + j] = make_float2(delta, c);
      }
    } else {
      float4 v;
      v.x = acc[i][0] + b4[0];
      v.y = acc[i][1] + b4[1];
      v.z = acc[i][2] + b4[2];
      v.w = acc[i][3] + b4[3];
      if constexpr (EPI == 1) {
        float4 r = *(const float4*)&res[(size_t)m * NN + nb];
        v.x += r.x; v.y += r.y; v.z += r.z; v.w += r.w;
      }
      *(float4*)&out[(size_t)m * NN + nb] = v;
    }
  }
}

// ---------------------------------------------------------------------------
// Selective scan. 16 lanes per (b,d) channel: lane q owns state n=q.
// Per step: dA = exp(delta*A[q]) (one v_exp per wave), st = dA*st + c*B[q],
// y = shfl-reduce(st*C[q]) over the 16-lane group. delta/c precomputed.
// ---------------------------------------------------------------------------
constexpr int DPB = 8;    // d-channels per block
constexpr int SCT = 128;  // threads (= DPB*16)
constexpr int CH  = 64;   // l-chunk staged in LDS

__device__ __forceinline__ void scan_dev(const float2* __restrict__ dc,
                                         const float*  __restrict__ xdbl,
                                         const float*  __restrict__ h,
                                         const float*  __restrict__ Alog,
                                         const float*  __restrict__ Dp,
                                         float* __restrict__ yout) {
  __shared__ float2 sDC[CH * DPB];
  __shared__ float  sH [CH * DPB];
  __shared__ float  sBC[CH * 32];   // per l: [0:16)=B, [16:32)=C
  const int tid = threadIdx.x;
  const int q  = tid & 15;          // state index n
  const int dq = tid >> 4;          // local d
  const int b  = blockIdx.x >> 6;   // D_/DPB = 64 blocks per batch
  const int d0 = (blockIdx.x & 63) * DPB;
  const int d  = d0 + dq;
  const float Aq  = -expf(Alog[d * N_ + q]);
  const float Dpv = Dp[d];
  const int rowbase = b * L_;
  float st = 0.0f;

  for (int l0 = 0; l0 < L_; l0 += CH) {
#pragma unroll
    for (int i = tid; i < CH * DPB; i += SCT) {   // 4 iters
      int lo = i >> 3, dl = i & 7;
      size_t g = (size_t)(rowbase + l0 + lo) * D_ + d0 + dl;
      sDC[i] = dc[g];
      sH[i]  = h[g];
    }
#pragma unroll
    for (int i = tid; i < CH * 32; i += SCT) {    // 16 iters
      int lo = i >> 5, c = i & 31;
      sBC[i] = xdbl[(size_t)(rowbase + l0 + lo) * RN_ + R_ + c];
    }
    __syncthreads();
#pragma unroll 4
    for (int l = 0; l < CH; ++l) {
      float2 dcv = sDC[l * DPB + dq];             // (delta, delta*h)
      float dA = __expf(dcv.x * Aq);              // arg <= 0, safe
      float bq = sBC[l * 32 + q];
      float cq = sBC[l * 32 + 16 + q];
      st = fmaf(dA, st, dcv.y * bq);
      float yp = st * cq;
      yp += __shfl_xor(yp, 1);
      yp += __shfl_xor(yp, 2);
      yp += __shfl_xor(yp, 4);
      yp += __shfl_xor(yp, 8);
      if (q == 0)
        yout[(size_t)(rowbase + l0 + l) * D_ + d] = yp + sH[l * DPB + dq] * Dpv;
    }
    __syncthreads();
  }
}

// ---------------------------------------------------------------------------
// Wrapper kernels binding device-global intermediates
// ---------------------------------------------------------------------------
__global__ __launch_bounds__(256) void k_in(const float* x, const float* w, const float* b) {
  gemm_dev<64, 64, 512, false, 0>(x, w, b, nullptr, g_h);
}
__global__ __launch_bounds__(256) void k_xdbl1(const float* xp) {
  gemm_dev<512, 512, 64, false, 3>(g_h, xp, nullptr, nullptr, g_xdbl);
}
__global__ __launch_bounds__(256) void k_delta1(const float* dtw, const float* dtb) {
  gemm_dev<32, 64, 512, false, 2>(g_xdbl, dtw, dtb, g_h, (float*)g_dc);
}
__global__ __launch_bounds__(SCT) void k_scan1(const float* Alog, const float* Dp) {
  scan_dev(g_dc, g_xdbl, g_h, Alog, Dp, g_y);
}
__global__ __launch_bounds__(256) void k_mix1(const float* w, const float* b) {
  gemm_dev<512, 512, 512, true, 1>(g_y, w, b, g_h, g_h2);
}
__global__ __launch_bounds__(256) void k_xdbl2(const float* xp) {
  gemm_dev<512, 512, 64, false, 3>(g_h2, xp, nullptr, nullptr, g_xdbl);
}
__global__ __launch_bounds__(256) void k_delta2(const float* dtw, const float* dtb) {
  gemm_dev<32, 64, 512, false, 2>(g_xdbl, dtw, dtb, g_h2, (float*)g_dc);
}
__global__ __launch_bounds__(SCT) void k_scan2(const float* Alog, const float* Dp) {
  scan_dev(g_dc, g_xdbl, g_h2, Alog, Dp, g_y);
}
__global__ __launch_bounds__(256) void k_mix2(const float* w, const float* b) {
  gemm_dev<512, 512, 512, true, 1>(g_y, w, b, g_h2, g_h);
}
__global__ __launch_bounds__(512) void k_final(const float* out_w, const float* out_b,
                                               float* out) {
  __shared__ float sm[D_];
  __shared__ float sp[DOUT_ * 16];
  const int b = blockIdx.x, tid = threadIdx.x;
  float acc = 0.0f;
  for (int l = 0; l < L_; ++l) acc += g_h[(size_t)(b * L_ + l) * D_ + tid];
  sm[tid] = acc * (1.0f / L_);
  __syncthreads();
  if (tid < DOUT_ * 16) {
    int o = tid >> 4, seg = tid & 15;
    float p = 0.0f;
#pragma unroll
    for (int i = 0; i < 32; ++i)
      p += sm[seg * 32 + i] * out_w[o * D_ + seg * 32 + i];
    sp[tid] = p;
  }
  __syncthreads();
  if (tid < DOUT_) {
    float s = out_b[tid];
#pragma unroll
    for (int i = 0; i < 16; ++i) s += sp[tid * 16 + i];
    out[b * DOUT_ + tid] = s;
  }
}

extern "C" void kernel_launch(void* const* d_in, const int* in_sizes, int n_in,
                              void* d_out, int out_size, void* d_ws, size_t ws_size,
                              hipStream_t stream) {
  const float* x        = (const float*)d_in[0];
  const float* W_in     = (const float*)d_in[1];
  const float* b_in     = (const float*)d_in[2];
  const float* mix1_w   = (const float*)d_in[3];
  const float* mix1_b   = (const float*)d_in[4];
  const float* mix2_w   = (const float*)d_in[5];
  const float* mix2_b   = (const float*)d_in[6];
  const float* out_w    = (const float*)d_in[7];
  const float* out_b    = (const float*)d_in[8];
  const float* m1_xproj = (const float*)d_in[9];
  const float* m1_dtw   = (const float*)d_in[10];
  const float* m1_dtb   = (const float*)d_in[11];
  const float* m1_Alog  = (const float*)d_in[12];
  const float* m1_D     = (const float*)d_in[13];
  const float* m2_xproj = (const float*)d_in[14];
  const float* m2_dtw   = (const float*)d_in[15];
  const float* m2_dtb   = (const float*)d_in[16];
  const float* m2_Alog  = (const float*)d_in[17];
  const float* m2_D     = (const float*)d_in[18];
  float* out = (float*)d_out;

  const int gFull = (M_ / 64) * (D_ / 64);   // 512 blocks
  const int gXdbl = (M_ / 64) * (RN_ / 64);  // 64 blocks
  const int gScan = B_ * (D_ / DPB);         // 256 blocks

  k_in    <<<gFull, 256, 0, stream>>>(x, W_in, b_in);
  k_xdbl1 <<<gXdbl, 256, 0, stream>>>(m1_xproj);
  k_delta1<<<gFull, 256, 0, stream>>>(m1_dtw, m1_dtb);
  k_scan1 <<<gScan, SCT, 0, stream>>>(m1_Alog, m1_D);
  k_mix1  <<<gFull, 256, 0, stream>>>(mix1_w, mix1_b);
  k_xdbl2 <<<gXdbl, 256, 0, stream>>>(m2_xproj);
  k_delta2<<<gFull, 256, 0, stream>>>(m2_dtw, m2_dtb);
  k_scan2 <<<gScan, SCT, 0, stream>>>(m2_Alog, m2_D);
  k_mix2  <<<gFull, 256, 0, stream>>>(mix2_w, mix2_b);
  k_final <<<B_,    512, 0, stream>>>(out_w, out_b, out);
}

// Round 2
// 403.132 us; speedup vs baseline: 2.0309x; 2.0309x over previous
//
#include <hip/hip_runtime.h>
#include <math.h>

// Problem dims
constexpr int B_   = 4;
constexpr int L_   = 1024;
constexpr int DIN_ = 64;
constexpr int DOUT_= 10;
constexpr int D_   = 512;
constexpr int N_   = 16;
constexpr int R_   = 32;
constexpr int RN_  = 64;          // R + 2N
constexpr int M_   = B_ * L_;     // 4096 rows (b,l) flattened

// Chunked scan config
constexpr int CN_ = 64;           // number of chunks over L
constexpr int CL_ = L_ / CN_;     // 16 steps per chunk

// Intermediates as device globals.
__device__ float  g_h   [M_ * D_];    // hidden after in-proj / after mix1
__device__ float  g_h2  [M_ * D_];    // hidden after mix1 (layer-2 input/residual)
__device__ float  g_y   [M_ * D_];    // raw mamba output (pre-GELU)
__device__ float  g_xdbl[M_ * RN_];   // [dt(32) | B(16) | C(16)] per row
__device__ float2 g_dc  [M_ * D_];    // (delta, delta*h) per (row,d)
// scan scratch
__device__ float  g_stL  [B_ * CN_ * D_ * N_];  // per-chunk local end state
__device__ float  g_sumd [B_ * CN_ * D_];       // per-chunk sum of delta
__device__ float  g_carry[B_ * CN_ * D_ * N_];  // per-chunk carry-in state

__device__ __forceinline__ float gelu_f(float x) {
  return 0.5f * x * (1.0f + erff(x * 0.7071067811865475f));
}
__device__ __forceinline__ float softplus_f(float x) {
  return fmaxf(x, 0.0f) + log1pf(__expf(-fabsf(x)));
}

// ---------------------------------------------------------------------------
// Generic fp32 tiled GEMM:  out[m,n] = sum_k A[m,k] * Bt[n,k]  (+ epilogue)
// BM=BN=64, BK=16, 256 threads, 4x4 per thread.  (unchanged from R1)
// EPI: 0=+bias  1=+bias+res  2=delta epilogue  3=plain
// ---------------------------------------------------------------------------
template<int K, int LDA, int NN, bool GELU_A, int EPI>
__device__ __forceinline__ void gemm_dev(const float* __restrict__ A,
                                         const float* __restrict__ Bt,
                                         const float* __restrict__ bias,
                                         const float* __restrict__ res,
                                         float* __restrict__ out) {
  __shared__ float As[16][68];
  __shared__ float Bs[16][68];
  const int tid = threadIdx.x;
  const int tx = tid & 15;
  const int ty = tid >> 4;
  const int lm = tid >> 2;
  const int lk = (tid & 3) << 2;
  constexpr int NB = NN / 64;
  const int m0 = (blockIdx.x / NB) * 64;
  const int n0 = (blockIdx.x % NB) * 64;

  float acc[4][4] = {};
  for (int k0 = 0; k0 < K; k0 += 16) {
    float4 av = *(const float4*)&A[(size_t)(m0 + lm) * LDA + k0 + lk];
    if (GELU_A) {
      av.x = gelu_f(av.x); av.y = gelu_f(av.y);
      av.z = gelu_f(av.z); av.w = gelu_f(av.w);
    }
    float4 bv = *(const float4*)&Bt[(size_t)(n0 + lm) * K + k0 + lk];
    As[lk + 0][lm] = av.x; As[lk + 1][lm] = av.y;
    As[lk + 2][lm] = av.z; As[lk + 3][lm] = av.w;
    Bs[lk + 0][lm] = bv.x; Bs[lk + 1][lm] = bv.y;
    Bs[lk + 2][lm] = bv.z; Bs[lk + 3][lm] = bv.w;
    __syncthreads();
#pragma unroll
    for (int k = 0; k < 16; ++k) {
      float4 a = *(const float4*)&As[k][ty << 2];
      float4 b = *(const float4*)&Bs[k][tx << 2];
      float aa[4] = {a.x, a.y, a.z, a.w};
      float bb[4] = {b.x, b.y, b.z, b.w};
#pragma unroll
      for (int i = 0; i < 4; ++i)
#pragma unroll
        for (int j = 0; j < 4; ++j)
          acc[i][j] = fmaf(aa[i], bb[j], acc[i][j]);
    }
    __syncthreads();
  }

  const int nb = n0 + (tx << 2);
  float b4[4] = {0.f, 0.f, 0.f, 0.f};
  if constexpr (EPI != 3) {
    float4 t = *(const float4*)&bias[nb];
    b4[0] = t.x; b4[1] = t.y; b4[2] = t.z; b4[3] = t.w;
  }
#pragma unroll
  for (int i = 0; i < 4; ++i) {
    const int m = m0 + (ty << 2) + i;
    if constexpr (EPI == 2) {
      const float* hrow = &res[(size_t)m * NN];
      float2* o2 = (float2*)out;
#pragma unroll
      for (int j = 0; j < 4; ++j) {
        float delta = softplus_f(acc[i][j] + b4[j]);
        float c = delta * hrow[nb + j];
        o2[(size_t)m * NN + nb + j] = make_float2(delta, c);
      }
    } else {
      float4 v;
      v.x = acc[i][0] + b4[0];
      v.y = acc[i][1] + b4[1];
      v.z = acc[i][2] + b4[2];
      v.w = acc[i][3] + b4[3];
      if constexpr (EPI == 1) {
        float4 r = *(const float4*)&res[(size_t)m * NN + nb];
        v.x += r.x; v.y += r.y; v.z += r.z; v.w += r.w;
      }
      *(float4*)&out[(size_t)m * NN + nb] = v;
    }
  }
}

// ---------------------------------------------------------------------------
// Chunked selective scan — thread-per-(b,d,chunk), 16 states in registers.
//   P1   : local scan from 0 over CL_ steps; store end-state + sum(delta)
//   carry: H_c = exp(A*sumd_c) * H_{c-1} + S_c   (serial over 64 chunks)
//   P2   : re-run chunk seeded with carry-in; emit y = st·C + h*Dp
// ---------------------------------------------------------------------------
__device__ __forceinline__ void load_A(const float* __restrict__ Alog, int d,
                                       float* A) {
#pragma unroll
  for (int n = 0; n < 16; n += 4) {
    float4 t = *(const float4*)&Alog[d * N_ + n];
    A[n + 0] = -__expf(t.x); A[n + 1] = -__expf(t.y);
    A[n + 2] = -__expf(t.z); A[n + 3] = -__expf(t.w);
  }
}

__device__ __forceinline__ void scan_p1_dev(const float2* __restrict__ dc,
                                            const float*  __restrict__ xdbl,
                                            const float*  __restrict__ Alog) {
  __shared__ float sB[CL_][16];
  const int d = threadIdx.x;              // 0..511
  const int c = blockIdx.x & (CN_ - 1);
  const int b = blockIdx.x / CN_;
  const int row0 = b * L_ + c * CL_;
  if (threadIdx.x < CL_ * 16) {
    int l = threadIdx.x >> 4, n = threadIdx.x & 15;
    sB[l][n] = xdbl[(size_t)(row0 + l) * RN_ + R_ + n];
  }
  float A[16];
  load_A(Alog, d, A);
  __syncthreads();

  float st[16] = {};
  float sumd = 0.0f;
#pragma unroll
  for (int l = 0; l < CL_; ++l) {
    float2 dcv = dc[(size_t)(row0 + l) * D_ + d];   // (delta, delta*h)
    sumd += dcv.x;
#pragma unroll
    for (int n = 0; n < 16; ++n) {
      float dA = __expf(dcv.x * A[n]);
      st[n] = fmaf(dA, st[n], dcv.y * sB[l][n]);
    }
  }
  const size_t o = ((size_t)(b * CN_ + c) * D_ + d) * N_;
#pragma unroll
  for (int n = 0; n < 16; n += 4)
    *(float4*)&g_stL[o + n] = make_float4(st[n], st[n+1], st[n+2], st[n+3]);
  g_sumd[(b * CN_ + c) * D_ + d] = sumd;
}

__global__ __launch_bounds__(256) void k_scan_carry(const float* __restrict__ Alog) {
  const int g = blockIdx.x * 256 + threadIdx.x;     // B*D*N = 32768 threads
  const int n = g & 15;
  const int d = (g >> 4) & (D_ - 1);
  const int b = g >> 13;
  const float A = -__expf(Alog[d * N_ + n]);
  float carry = 0.0f;
#pragma unroll 4
  for (int c = 0; c < CN_; ++c) {
    const size_t idx = ((size_t)(b * CN_ + c) * D_ + d) * N_ + n;
    g_carry[idx] = carry;
    float P = __expf(A * g_sumd[(b * CN_ + c) * D_ + d]);
    carry = fmaf(P, carry, g_stL[idx]);
  }
}

__device__ __forceinline__ void scan_p2_dev(const float2* __restrict__ dc,
                                            const float*  __restrict__ xdbl,
                                            const float*  __restrict__ h,
                                            const float*  __restrict__ Alog,
                                            const float*  __restrict__ Dp,
                                            float* __restrict__ yout) {
  __shared__ float sBC[CL_][32];          // [0:16)=B, [16:32)=C
  const int d = threadIdx.x;
  const int c = blockIdx.x & (CN_ - 1);
  const int b = blockIdx.x / CN_;
  const int row0 = b * L_ + c * CL_;
  {
    int l = threadIdx.x >> 5, idx = threadIdx.x & 31;   // 512 = 16*32
    sBC[l][idx] = xdbl[(size_t)(row0 + l) * RN_ + R_ + idx];
  }
  float A[16];
  load_A(Alog, d, A);
  const float Dpv = Dp[d];
  __syncthreads();

  float st[16];
  const size_t o = ((size_t)(b * CN_ + c) * D_ + d) * N_;
#pragma unroll
  for (int n = 0; n < 16; n += 4) {
    float4 t = *(const float4*)&g_carry[o + n];
    st[n] = t.x; st[n+1] = t.y; st[n+2] = t.z; st[n+3] = t.w;
  }
#pragma unroll
  for (int l = 0; l < CL_; ++l) {
    float2 dcv = dc[(size_t)(row0 + l) * D_ + d];
    float y = 0.0f;
#pragma unroll
    for (int n = 0; n < 16; ++n) {
      float dA = __expf(dcv.x * A[n]);
      st[n] = fmaf(dA, st[n], dcv.y * sBC[l][n]);
      y = fmaf(st[n], sBC[l][16 + n], y);
    }
    float hv = h[(size_t)(row0 + l) * D_ + d];
    yout[(size_t)(row0 + l) * D_ + d] = y + hv * Dpv;
  }
}

// ---------------------------------------------------------------------------
// Wrapper kernels
// ---------------------------------------------------------------------------
__global__ __launch_bounds__(256) void k_in(const float* x, const float* w, const float* b) {
  gemm_dev<64, 64, 512, false, 0>(x, w, b, nullptr, g_h);
}
__global__ __launch_bounds__(256) void k_xdbl1(const float* xp) {
  gemm_dev<512, 512, 64, false, 3>(g_h, xp, nullptr, nullptr, g_xdbl);
}
__global__ __launch_bounds__(256) void k_delta1(const float* dtw, const float* dtb) {
  gemm_dev<32, 64, 512, false, 2>(g_xdbl, dtw, dtb, g_h, (float*)g_dc);
}
__global__ __launch_bounds__(512) void k_scan1_p1(const float* Alog) {
  scan_p1_dev(g_dc, g_xdbl, Alog);
}
__global__ __launch_bounds__(512) void k_scan1_p2(const float* Alog, const float* Dp) {
  scan_p2_dev(g_dc, g_xdbl, g_h, Alog, Dp, g_y);
}
__global__ __launch_bounds__(256) void k_mix1(const float* w, const float* b) {
  gemm_dev<512, 512, 512, true, 1>(g_y, w, b, g_h, g_h2);
}
__global__ __launch_bounds__(256) void k_xdbl2(const float* xp) {
  gemm_dev<512, 512, 64, false, 3>(g_h2, xp, nullptr, nullptr, g_xdbl);
}
__global__ __launch_bounds__(256) void k_delta2(const float* dtw, const float* dtb) {
  gemm_dev<32, 64, 512, false, 2>(g_xdbl, dtw, dtb, g_h2, (float*)g_dc);
}
__global__ __launch_bounds__(512) void k_scan2_p1(const float* Alog) {
  scan_p1_dev(g_dc, g_xdbl, Alog);
}
__global__ __launch_bounds__(512) void k_scan2_p2(const float* Alog, const float* Dp) {
  scan_p2_dev(g_dc, g_xdbl, g_h2, Alog, Dp, g_y);
}
__global__ __launch_bounds__(256) void k_mix2(const float* w, const float* b) {
  gemm_dev<512, 512, 512, true, 1>(g_y, w, b, g_h2, g_h);
}
__global__ __launch_bounds__(512) void k_final(const float* out_w, const float* out_b,
                                               float* out) {
  __shared__ float sm[D_];
  __shared__ float sp[DOUT_ * 16];
  const int b = blockIdx.x, tid = threadIdx.x;
  float acc = 0.0f;
  for (int l = 0; l < L_; ++l) acc += g_h[(size_t)(b * L_ + l) * D_ + tid];
  sm[tid] = acc * (1.0f / L_);
  __syncthreads();
  if (tid < DOUT_ * 16) {
    int o = tid >> 4, seg = tid & 15;
    float p = 0.0f;
#pragma unroll
    for (int i = 0; i < 32; ++i)
      p += sm[seg * 32 + i] * out_w[o * D_ + seg * 32 + i];
    sp[tid] = p;
  }
  __syncthreads();
  if (tid < DOUT_) {
    float s = out_b[tid];
#pragma unroll
    for (int i = 0; i < 16; ++i) s += sp[tid * 16 + i];
    out[b * DOUT_ + tid] = s;
  }
}

extern "C" void kernel_launch(void* const* d_in, const int* in_sizes, int n_in,
                              void* d_out, int out_size, void* d_ws, size_t ws_size,
                              hipStream_t stream) {
  const float* x        = (const float*)d_in[0];
  const float* W_in     = (const float*)d_in[1];
  const float* b_in     = (const float*)d_in[2];
  const float* mix1_w   = (const float*)d_in[3];
  const float* mix1_b   = (const float*)d_in[4];
  const float* mix2_w   = (const float*)d_in[5];
  const float* mix2_b   = (const float*)d_in[6];
  const float* out_w    = (const float*)d_in[7];
  const float* out_b    = (const float*)d_in[8];
  const float* m1_xproj = (const float*)d_in[9];
  const float* m1_dtw   = (const float*)d_in[10];
  const float* m1_dtb   = (const float*)d_in[11];
  const float* m1_Alog  = (const float*)d_in[12];
  const float* m1_D     = (const float*)d_in[13];
  const float* m2_xproj = (const float*)d_in[14];
  const float* m2_dtw   = (const float*)d_in[15];
  const float* m2_dtb   = (const float*)d_in[16];
  const float* m2_Alog  = (const float*)d_in[17];
  const float* m2_D     = (const float*)d_in[18];
  float* out = (float*)d_out;

  const int gFull  = (M_ / 64) * (D_ / 64);   // 512 blocks
  const int gXdbl  = (M_ / 64) * (RN_ / 64);  // 64 blocks
  const int gScan  = B_ * CN_;                // 256 blocks
  const int gCarry = (B_ * D_ * N_) / 256;    // 128 blocks

  k_in      <<<gFull,  256, 0, stream>>>(x, W_in, b_in);
  k_xdbl1   <<<gXdbl,  256, 0, stream>>>(m1_xproj);
  k_delta1  <<<gFull,  256, 0, stream>>>(m1_dtw, m1_dtb);
  k_scan1_p1<<<gScan,  512, 0, stream>>>(m1_Alog);
  k_scan_carry<<<gCarry, 256, 0, stream>>>(m1_Alog);
  k_scan1_p2<<<gScan,  512, 0, stream>>>(m1_Alog, m1_D);
  k_mix1    <<<gFull,  256, 0, stream>>>(mix1_w, mix1_b);
  k_xdbl2   <<<gXdbl,  256, 0, stream>>>(m2_xproj);
  k_delta2  <<<gFull,  256, 0, stream>>>(m2_dtw, m2_dtb);
  k_scan2_p1<<<gScan,  512, 0, stream>>>(m2_Alog);
  k_scan_carry<<<gCarry, 256, 0, stream>>>(m2_Alog);
  k_scan2_p2<<<gScan,  512, 0, stream>>>(m2_Alog, m2_D);
  k_mix2    <<<gFull,  256, 0, stream>>>(mix2_w, mix2_b);
  k_final   <<<B_,     512, 0, stream>>>(out_w, out_b, out);
}

// Round 4
// 249.975 us; speedup vs baseline: 3.2752x; 1.6127x over previous
//
#include <hip/hip_runtime.h>
#include <math.h>

typedef unsigned short ushort_t;
typedef short bf8_t __attribute__((ext_vector_type(8)));   // 8 bf16 in 4 VGPRs
typedef float f4_t  __attribute__((ext_vector_type(4)));

// Problem dims
constexpr int B_   = 4;
constexpr int L_   = 1024;
constexpr int DIN_ = 64;
constexpr int DOUT_= 10;
constexpr int D_   = 512;
constexpr int N_   = 16;
constexpr int R_   = 32;
constexpr int RN_  = 64;          // R + 2N
constexpr int M_   = B_ * L_;     // 4096 rows (b,l) flattened

// Chunked scan config
constexpr int CN_ = 64;           // chunks over L
constexpr int CL_ = L_ / CN_;     // 16 steps per chunk

// Intermediates (device globals; referenced ONLY inside device code —
// passing these as host-side kernel args was the round-3 crash).
__device__ float    g_h   [M_ * D_];    // hidden fp32 (layer-1 input / residual)
__device__ float    g_h2  [M_ * D_];    // hidden fp32 (layer-2 input / residual)
__device__ ushort_t g_hbf [M_ * D_];    // bf16 copy of current hidden (xdbl A-operand)
__device__ ushort_t g_gelubf[M_ * D_];  // bf16(gelu(mamba_y)) (mix A-operand)
__device__ float    g_xdbl[M_ * RN_];   // [dt(32) | B(16) | C(16)]
__device__ float2   g_dc  [M_ * D_];    // (delta, delta*h)
__device__ float    g_stL  [B_ * CN_ * D_ * N_];
__device__ float    g_sumd [B_ * CN_ * D_];
__device__ float    g_carry[B_ * CN_ * D_ * N_];
__device__ float    g_part [B_ * 16 * D_];
// bf16 weights (re-converted each call)
__device__ ushort_t g_w1bf [D_ * D_];
__device__ ushort_t g_w2bf [D_ * D_];
__device__ ushort_t g_xp1bf[RN_ * D_];
__device__ ushort_t g_xp2bf[RN_ * D_];

__device__ __forceinline__ float gelu_f(float x) {
  return 0.5f * x * (1.0f + erff(x * 0.7071067811865475f));
}
__device__ __forceinline__ float softplus_f(float x) {
  return fmaxf(x, 0.0f) + log1pf(__expf(-fabsf(x)));
}
__device__ __forceinline__ ushort_t f2bf(float x) {  // RNE fp32->bf16
  union { float f; unsigned u; } v; v.f = x;
  unsigned r = v.u + 0x7fffu + ((v.u >> 16) & 1u);
  return (ushort_t)(r >> 16);
}

// ---------------------------------------------------------------------------
// Weight fp32->bf16 conversion (every call; no static state allowed)
// ---------------------------------------------------------------------------
__global__ __launch_bounds__(256) void k_cvt(const float* __restrict__ w1,
                                             const float* __restrict__ w2,
                                             const float* __restrict__ xp1,
                                             const float* __restrict__ xp2) {
  int i = (blockIdx.x * 256 + threadIdx.x) * 4;
  const float* src; ushort_t* dst; int off;
  if (i < 262144)      { src = w1;  dst = g_w1bf;  off = i; }
  else if (i < 524288) { src = w2;  dst = g_w2bf;  off = i - 262144; }
  else if (i < 557056) { src = xp1; dst = g_xp1bf; off = i - 524288; }
  else                 { src = xp2; dst = g_xp2bf; off = i - 557056; }
  float4 v = *(const float4*)&src[off];
  ushort4 o; o.x = f2bf(v.x); o.y = f2bf(v.y); o.z = f2bf(v.z); o.w = f2bf(v.w);
  *(ushort4*)&dst[off] = o;
}

// ---------------------------------------------------------------------------
// bf16 MFMA GEMM (device fn): out[m,n] = sum_k A[m,k]*Wt[n,k], K=512 bf16.
// 64x64 tile, BK=64, 256 thr = 4 waves, each wave 32x32 via 2x2 16x16x32 MFMA.
// EPIM: 0 = plain fp32 store; 1 = +bias +res (fp32) store. DUAL: also bf16.
// ---------------------------------------------------------------------------
template<int NN, int EPIM, bool DUAL>
__device__ __forceinline__ void gemm_bf16_dev(
    const ushort_t* __restrict__ Abf, const ushort_t* __restrict__ Wbf,
    const float* __restrict__ bias, const float* __restrict__ res,
    float* __restrict__ out, ushort_t* __restrict__ obf) {
  __shared__ ushort_t As[64][72];
  __shared__ ushort_t Bs[64][72];
  constexpr int NB = NN / 64;
  const int tid  = threadIdx.x;
  const int m0   = (blockIdx.x / NB) * 64;
  const int n0   = (blockIdx.x % NB) * 64;
  const int lane = tid & 63;
  const int wv   = tid >> 6;
  const int quad = lane >> 4;
  const int ln   = lane & 15;
  const int mw   = (wv & 1) * 32;
  const int nw   = (wv >> 1) * 32;

  f4_t acc[2][2] = {};

  for (int k0 = 0; k0 < 512; k0 += 64) {
#pragma unroll
    for (int c = 0; c < 2; ++c) {
      int idx = tid + c * 256;                 // 512 chunks of 8 bf16
      int m = idx >> 3, kq = (idx & 7) << 3;
      *(float4*)&As[m][kq] = *(const float4*)&Abf[(size_t)(m0 + m) * 512 + k0 + kq];
      *(float4*)&Bs[m][kq] = *(const float4*)&Wbf[(size_t)(n0 + m) * 512 + k0 + kq];
    }
    __syncthreads();
#pragma unroll
    for (int k1 = 0; k1 < 64; k1 += 32) {
      bf8_t a0 = *(const bf8_t*)&As[mw +      ln][k1 + quad * 8];
      bf8_t a1 = *(const bf8_t*)&As[mw + 16 + ln][k1 + quad * 8];
      bf8_t b0 = *(const bf8_t*)&Bs[nw +      ln][k1 + quad * 8];
      bf8_t b1 = *(const bf8_t*)&Bs[nw + 16 + ln][k1 + quad * 8];
      acc[0][0] = __builtin_amdgcn_mfma_f32_16x16x32_bf16(a0, b0, acc[0][0], 0, 0, 0);
      acc[0][1] = __builtin_amdgcn_mfma_f32_16x16x32_bf16(a0, b1, acc[0][1], 0, 0, 0);
      acc[1][0] = __builtin_amdgcn_mfma_f32_16x16x32_bf16(a1, b0, acc[1][0], 0, 0, 0);
      acc[1][1] = __builtin_amdgcn_mfma_f32_16x16x32_bf16(a1, b1, acc[1][1], 0, 0, 0);
    }
    __syncthreads();
  }

  float bj[2] = {0.f, 0.f};
  if constexpr (EPIM == 1) {
    bj[0] = bias[n0 + nw + ln];
    bj[1] = bias[n0 + nw + 16 + ln];
  }
#pragma unroll
  for (int i = 0; i < 2; ++i)
#pragma unroll
    for (int j = 0; j < 2; ++j) {
      const int nc = n0 + nw + 16 * j + ln;
#pragma unroll
      for (int r = 0; r < 4; ++r) {
        const int row = m0 + mw + 16 * i + quad * 4 + r;
        const size_t idx = (size_t)row * NN + nc;
        float v = acc[i][j][r];
        if constexpr (EPIM == 1) v += bj[j] + res[idx];
        out[idx] = v;
        if constexpr (DUAL) obf[idx] = f2bf(v);
      }
    }
}

// Wrappers binding device globals IN DEVICE CODE (the round-3 fix).
__global__ __launch_bounds__(256) void k_xdbl1g() {
  gemm_bf16_dev<64, 0, false>(g_hbf, g_xp1bf, nullptr, nullptr, g_xdbl, nullptr);
}
__global__ __launch_bounds__(256) void k_xdbl2g() {
  gemm_bf16_dev<64, 0, false>(g_hbf, g_xp2bf, nullptr, nullptr, g_xdbl, nullptr);
}
__global__ __launch_bounds__(256) void k_mix1g(const float* __restrict__ bias) {
  gemm_bf16_dev<512, 1, true>(g_gelubf, g_w1bf, bias, g_h, g_h2, g_hbf);
}
__global__ __launch_bounds__(256) void k_mix2g(const float* __restrict__ bias) {
  gemm_bf16_dev<512, 1, false>(g_gelubf, g_w2bf, bias, g_h2, g_h, nullptr);
}

// ---------------------------------------------------------------------------
// fp32 tiled GEMM (in-proj and delta-proj; K small).
// EPI: 2 = delta epilogue (softplus -> (delta, delta*h));  4 = +bias, dual store
// ---------------------------------------------------------------------------
template<int K, int LDA, int NN, int EPI>
__device__ __forceinline__ void gemm_dev(const float* __restrict__ A,
                                         const float* __restrict__ Bt,
                                         const float* __restrict__ bias,
                                         const float* __restrict__ res,
                                         float* __restrict__ out,
                                         ushort_t* __restrict__ obf) {
  __shared__ float As[16][68];
  __shared__ float Bs[16][68];
  const int tid = threadIdx.x;
  const int tx = tid & 15;
  const int ty = tid >> 4;
  const int lm = tid >> 2;
  const int lk = (tid & 3) << 2;
  constexpr int NB = NN / 64;
  const int m0 = (blockIdx.x / NB) * 64;
  const int n0 = (blockIdx.x % NB) * 64;

  float acc[4][4] = {};
  for (int k0 = 0; k0 < K; k0 += 16) {
    float4 av = *(const float4*)&A[(size_t)(m0 + lm) * LDA + k0 + lk];
    float4 bv = *(const float4*)&Bt[(size_t)(n0 + lm) * K + k0 + lk];
    As[lk + 0][lm] = av.x; As[lk + 1][lm] = av.y;
    As[lk + 2][lm] = av.z; As[lk + 3][lm] = av.w;
    Bs[lk + 0][lm] = bv.x; Bs[lk + 1][lm] = bv.y;
    Bs[lk + 2][lm] = bv.z; Bs[lk + 3][lm] = bv.w;
    __syncthreads();
#pragma unroll
    for (int k = 0; k < 16; ++k) {
      float4 a = *(const float4*)&As[k][ty << 2];
      float4 b = *(const float4*)&Bs[k][tx << 2];
      float aa[4] = {a.x, a.y, a.z, a.w};
      float bb[4] = {b.x, b.y, b.z, b.w};
#pragma unroll
      for (int i = 0; i < 4; ++i)
#pragma unroll
        for (int j = 0; j < 4; ++j)
          acc[i][j] = fmaf(aa[i], bb[j], acc[i][j]);
    }
    __syncthreads();
  }

  const int nb = n0 + (tx << 2);
  float4 t = *(const float4*)&bias[nb];
  float b4[4] = {t.x, t.y, t.z, t.w};
#pragma unroll
  for (int i = 0; i < 4; ++i) {
    const int m = m0 + (ty << 2) + i;
    if constexpr (EPI == 2) {
      const float* hrow = &res[(size_t)m * NN];
      float2* o2 = (float2*)out;
#pragma unroll
      for (int j = 0; j < 4; ++j) {
        float delta = softplus_f(acc[i][j] + b4[j]);
        float c = delta * hrow[nb + j];
        o2[(size_t)m * NN + nb + j] = make_float2(delta, c);
      }
    } else {  // EPI == 4
      float4 v;
      v.x = acc[i][0] + b4[0];
      v.y = acc[i][1] + b4[1];
      v.z = acc[i][2] + b4[2];
      v.w = acc[i][3] + b4[3];
      *(float4*)&out[(size_t)m * NN + nb] = v;
      ushort4 o; o.x = f2bf(v.x); o.y = f2bf(v.y); o.z = f2bf(v.z); o.w = f2bf(v.w);
      *(ushort4*)&obf[(size_t)m * NN + nb] = o;
    }
  }
}

// ---------------------------------------------------------------------------
// Chunked selective scan (p2 emits bf16(gelu(y)))
// ---------------------------------------------------------------------------
__device__ __forceinline__ void load_A(const float* __restrict__ Alog, int d,
                                       float* A) {
#pragma unroll
  for (int n = 0; n < 16; n += 4) {
    float4 t = *(const float4*)&Alog[d * N_ + n];
    A[n + 0] = -__expf(t.x); A[n + 1] = -__expf(t.y);
    A[n + 2] = -__expf(t.z); A[n + 3] = -__expf(t.w);
  }
}

__device__ __forceinline__ void scan_p1_dev(const float2* __restrict__ dc,
                                            const float*  __restrict__ xdbl,
                                            const float*  __restrict__ Alog) {
  __shared__ float sB[CL_][16];
  const int d = threadIdx.x;
  const int c = blockIdx.x & (CN_ - 1);
  const int b = blockIdx.x / CN_;
  const int row0 = b * L_ + c * CL_;
  if (threadIdx.x < CL_ * 16) {
    int l = threadIdx.x >> 4, n = threadIdx.x & 15;
    sB[l][n] = xdbl[(size_t)(row0 + l) * RN_ + R_ + n];
  }
  float A[16];
  load_A(Alog, d, A);
  __syncthreads();

  float st[16] = {};
  float sumd = 0.0f;
#pragma unroll
  for (int l = 0; l < CL_; ++l) {
    float2 dcv = dc[(size_t)(row0 + l) * D_ + d];
    sumd += dcv.x;
#pragma unroll
    for (int n = 0; n < 16; ++n) {
      float dA = __expf(dcv.x * A[n]);
      st[n] = fmaf(dA, st[n], dcv.y * sB[l][n]);
    }
  }
  const size_t o = ((size_t)(b * CN_ + c) * D_ + d) * N_;
#pragma unroll
  for (int n = 0; n < 16; n += 4)
    *(float4*)&g_stL[o + n] = make_float4(st[n], st[n+1], st[n+2], st[n+3]);
  g_sumd[(b * CN_ + c) * D_ + d] = sumd;
}

__global__ __launch_bounds__(256) void k_scan_carry(const float* __restrict__ Alog) {
  const int g = blockIdx.x * 256 + threadIdx.x;
  const int n = g & 15;
  const int d = (g >> 4) & (D_ - 1);
  const int b = g >> 13;
  const float A = -__expf(Alog[d * N_ + n]);
  float carry = 0.0f;
#pragma unroll 4
  for (int c = 0; c < CN_; ++c) {
    const size_t idx = ((size_t)(b * CN_ + c) * D_ + d) * N_ + n;
    g_carry[idx] = carry;
    float P = __expf(A * g_sumd[(b * CN_ + c) * D_ + d]);
    carry = fmaf(P, carry, g_stL[idx]);
  }
}

__device__ __forceinline__ void scan_p2_dev(const float2* __restrict__ dc,
                                            const float*  __restrict__ xdbl,
                                            const float*  __restrict__ h,
                                            const float*  __restrict__ Alog,
                                            const float*  __restrict__ Dp,
                                            ushort_t* __restrict__ ybf) {
  __shared__ float sBC[CL_][32];
  const int d = threadIdx.x;
  const int c = blockIdx.x & (CN_ - 1);
  const int b = blockIdx.x / CN_;
  const int row0 = b * L_ + c * CL_;
  {
    int l = threadIdx.x >> 5, idx = threadIdx.x & 31;
    sBC[l][idx] = xdbl[(size_t)(row0 + l) * RN_ + R_ + idx];
  }
  float A[16];
  load_A(Alog, d, A);
  const float Dpv = Dp[d];
  __syncthreads();

  float st[16];
  const size_t o = ((size_t)(b * CN_ + c) * D_ + d) * N_;
#pragma unroll
  for (int n = 0; n < 16; n += 4) {
    float4 t = *(const float4*)&g_carry[o + n];
    st[n] = t.x; st[n+1] = t.y; st[n+2] = t.z; st[n+3] = t.w;
  }
#pragma unroll
  for (int l = 0; l < CL_; ++l) {
    float2 dcv = dc[(size_t)(row0 + l) * D_ + d];
    float y = 0.0f;
#pragma unroll
    for (int n = 0; n < 16; ++n) {
      float dA = __expf(dcv.x * A[n]);
      st[n] = fmaf(dA, st[n], dcv.y * sBC[l][n]);
      y = fmaf(st[n], sBC[l][16 + n], y);
    }
    float hv = h[(size_t)(row0 + l) * D_ + d];
    ybf[(size_t)(row0 + l) * D_ + d] = f2bf(gelu_f(y + hv * Dpv));
  }
}

// ---------------------------------------------------------------------------
// Wrapper kernels
// ---------------------------------------------------------------------------
__global__ __launch_bounds__(256) void k_in(const float* x, const float* w, const float* b) {
  gemm_dev<64, 64, 512, 4>(x, w, b, nullptr, g_h, g_hbf);
}
__global__ __launch_bounds__(256) void k_delta1(const float* dtw, const float* dtb) {
  gemm_dev<32, 64, 512, 2>(g_xdbl, dtw, dtb, g_h, (float*)g_dc, nullptr);
}
__global__ __launch_bounds__(256) void k_delta2(const float* dtw, const float* dtb) {
  gemm_dev<32, 64, 512, 2>(g_xdbl, dtw, dtb, g_h2, (float*)g_dc, nullptr);
}
__global__ __launch_bounds__(512) void k_scan1_p1(const float* Alog) {
  scan_p1_dev(g_dc, g_xdbl, Alog);
}
__global__ __launch_bounds__(512) void k_scan1_p2(const float* Alog, const float* Dp) {
  scan_p2_dev(g_dc, g_xdbl, g_h, Alog, Dp, g_gelubf);
}
__global__ __launch_bounds__(512) void k_scan2_p1(const float* Alog) {
  scan_p1_dev(g_dc, g_xdbl, Alog);
}
__global__ __launch_bounds__(512) void k_scan2_p2(const float* Alog, const float* Dp) {
  scan_p2_dev(g_dc, g_xdbl, g_h2, Alog, Dp, g_gelubf);
}

__global__ __launch_bounds__(256) void k_finalA() {
  const int b = blockIdx.x >> 4, c = blockIdx.x & 15;
  const int row0 = b * L_ + c * 64;
  float s0 = 0.f, s1 = 0.f;
  for (int l = 0; l < 64; ++l) {
    s0 += g_h[(size_t)(row0 + l) * D_ + threadIdx.x];
    s1 += g_h[(size_t)(row0 + l) * D_ + threadIdx.x + 256];
  }
  g_part[(size_t)blockIdx.x * D_ + threadIdx.x] = s0;
  g_part[(size_t)blockIdx.x * D_ + threadIdx.x + 256] = s1;
}
__global__ __launch_bounds__(512) void k_finalB(const float* out_w, const float* out_b,
                                                float* out) {
  __shared__ float sm[D_];
  __shared__ float sp[DOUT_ * 16];
  const int b = blockIdx.x, tid = threadIdx.x;
  float s = 0.f;
#pragma unroll
  for (int c = 0; c < 16; ++c) s += g_part[(size_t)(b * 16 + c) * D_ + tid];
  sm[tid] = s * (1.0f / L_);
  __syncthreads();
  if (tid < DOUT_ * 16) {
    int o = tid >> 4, seg = tid & 15;
    float p = 0.0f;
#pragma unroll
    for (int i = 0; i < 32; ++i)
      p += sm[seg * 32 + i] * out_w[o * D_ + seg * 32 + i];
    sp[tid] = p;
  }
  __syncthreads();
  if (tid < DOUT_) {
    float v = out_b[tid];
#pragma unroll
    for (int i = 0; i < 16; ++i) v += sp[tid * 16 + i];
    out[b * DOUT_ + tid] = v;
  }
}

extern "C" void kernel_launch(void* const* d_in, const int* in_sizes, int n_in,
                              void* d_out, int out_size, void* d_ws, size_t ws_size,
                              hipStream_t stream) {
  const float* x        = (const float*)d_in[0];
  const float* W_in     = (const float*)d_in[1];
  const float* b_in     = (const float*)d_in[2];
  const float* mix1_w   = (const float*)d_in[3];
  const float* mix1_b   = (const float*)d_in[4];
  const float* mix2_w   = (const float*)d_in[5];
  const float* mix2_b   = (const float*)d_in[6];
  const float* out_w    = (const float*)d_in[7];
  const float* out_b    = (const float*)d_in[8];
  const float* m1_xproj = (const float*)d_in[9];
  const float* m1_dtw   = (const float*)d_in[10];
  const float* m1_dtb   = (const float*)d_in[11];
  const float* m1_Alog  = (const float*)d_in[12];
  const float* m1_D     = (const float*)d_in[13];
  const float* m2_xproj = (const float*)d_in[14];
  const float* m2_dtw   = (const float*)d_in[15];
  const float* m2_dtb   = (const float*)d_in[16];
  const float* m2_Alog  = (const float*)d_in[17];
  const float* m2_D     = (const float*)d_in[18];
  float* out = (float*)d_out;

  const int gFull  = (M_ / 64) * (D_ / 64);   // 512
  const int gScan  = B_ * CN_;                // 256
  const int gCarry = (B_ * D_ * N_) / 256;    // 128
  const int gMix   = (M_ / 64) * (D_ / 64);   // 512
  const int gXdbl  = (M_ / 64);               // 64

  k_cvt<<<576, 256, 0, stream>>>(mix1_w, mix2_w, m1_xproj, m2_xproj);
  k_in <<<gFull, 256, 0, stream>>>(x, W_in, b_in);

  // ---- layer 1 ----
  k_xdbl1g  <<<gXdbl, 256, 0, stream>>>();
  k_delta1  <<<gFull, 256, 0, stream>>>(m1_dtw, m1_dtb);
  k_scan1_p1<<<gScan, 512, 0, stream>>>(m1_Alog);
  k_scan_carry<<<gCarry, 256, 0, stream>>>(m1_Alog);
  k_scan1_p2<<<gScan, 512, 0, stream>>>(m1_Alog, m1_D);
  k_mix1g   <<<gMix,  256, 0, stream>>>(mix1_b);
  // ---- layer 2 ----
  k_xdbl2g  <<<gXdbl, 256, 0, stream>>>();
  k_delta2  <<<gFull, 256, 0, stream>>>(m2_dtw, m2_dtb);
  k_scan2_p1<<<gScan, 512, 0, stream>>>(m2_Alog);
  k_scan_carry<<<gCarry, 256, 0, stream>>>(m2_Alog);
  k_scan2_p2<<<gScan, 512, 0, stream>>>(m2_Alog, m2_D);
  k_mix2g   <<<gMix,  256, 0, stream>>>(mix2_b);
  // ---- head ----
  k_finalA<<<B_ * 16, 256, 0, stream>>>();
  k_finalB<<<B_,      512, 0, stream>>>(out_w, out_b, out);
}

// Round 5
// 244.581 us; speedup vs baseline: 3.3475x; 1.0221x over previous
//
#include <hip/hip_runtime.h>
#include <math.h>

typedef unsigned short ushort_t;
typedef short bf8_t __attribute__((ext_vector_type(8)));   // 8 bf16 in 4 VGPRs
typedef float f4_t  __attribute__((ext_vector_type(4)));

// Problem dims
constexpr int B_   = 4;
constexpr int L_   = 1024;
constexpr int DIN_ = 64;
constexpr int DOUT_= 10;
constexpr int D_   = 512;
constexpr int N_   = 16;
constexpr int R_   = 32;
constexpr int RN_  = 64;          // R + 2N
constexpr int M_   = B_ * L_;     // 4096 rows (b,l) flattened

// Chunked scan config
constexpr int CN_ = 64;           // chunks over L
constexpr int CL_ = L_ / CN_;     // 16 steps per chunk

// Intermediates (device globals; referenced ONLY inside device code).
__device__ float    g_h   [M_ * D_];    // hidden fp32 (layer-1 input / residual)
__device__ float    g_h2  [M_ * D_];    // hidden fp32 (layer-2 input / residual)
__device__ ushort_t g_hbf [M_ * D_];    // bf16 copy of current hidden (xdbl A-operand)
__device__ ushort_t g_gelubf[M_ * D_];  // bf16(gelu(mamba_y)) (mix A-operand)
__device__ float    g_xdbl[M_ * RN_];   // [dt(32) | B(16) | C(16)]
__device__ float2   g_dc  [M_ * D_];    // (delta, delta*h)
__device__ float    g_stL  [B_ * CN_ * D_ * N_];
__device__ float    g_sumd [B_ * CN_ * D_];
__device__ float    g_carry[B_ * CN_ * D_ * N_];
__device__ float    g_mean [B_ * D_];   // column sums of final hidden (atomics)
// bf16 weights (re-converted each call)
__device__ ushort_t g_w1bf [D_ * D_];
__device__ ushort_t g_w2bf [D_ * D_];
__device__ ushort_t g_xp1bf[RN_ * D_];
__device__ ushort_t g_xp2bf[RN_ * D_];

__device__ __forceinline__ float gelu_f(float x) {
  return 0.5f * x * (1.0f + erff(x * 0.7071067811865475f));
}
__device__ __forceinline__ float softplus_f(float x) {
  return fmaxf(x, 0.0f) + log1pf(__expf(-fabsf(x)));
}
__device__ __forceinline__ ushort_t f2bf(float x) {  // RNE fp32->bf16
  union { float f; unsigned u; } v; v.f = x;
  unsigned r = v.u + 0x7fffu + ((v.u >> 16) & 1u);
  return (ushort_t)(r >> 16);
}

// ---------------------------------------------------------------------------
// Weight fp32->bf16 conversion + g_mean zeroing (every call)
// ---------------------------------------------------------------------------
__global__ __launch_bounds__(256) void k_cvt(const float* __restrict__ w1,
                                             const float* __restrict__ w2,
                                             const float* __restrict__ xp1,
                                             const float* __restrict__ xp2) {
  if (blockIdx.x == 576) {            // zero the mean accumulator (B*D = 2048)
#pragma unroll
    for (int j = 0; j < 8; ++j) g_mean[threadIdx.x * 8 + j] = 0.0f;
    return;
  }
  int i = (blockIdx.x * 256 + threadIdx.x) * 4;
  const float* src; ushort_t* dst; int off;
  if (i < 262144)      { src = w1;  dst = g_w1bf;  off = i; }
  else if (i < 524288) { src = w2;  dst = g_w2bf;  off = i - 262144; }
  else if (i < 557056) { src = xp1; dst = g_xp1bf; off = i - 524288; }
  else                 { src = xp2; dst = g_xp2bf; off = i - 557056; }
  float4 v = *(const float4*)&src[off];
  ushort4 o; o.x = f2bf(v.x); o.y = f2bf(v.y); o.z = f2bf(v.z); o.w = f2bf(v.w);
  *(ushort4*)&dst[off] = o;
}

// ---------------------------------------------------------------------------
// bf16 MFMA GEMM (K=512): out[m,n] = sum_k A[m,k]*Wt[n,k].
// 64x64 tile, BK=64, 256 thr = 4 waves, wave = 32x32 via 2x2 16x16x32 MFMA.
// EPIM: 0 = plain fp32; 1 = +bias +res. DUAL: also store bf16.
// MEAN: accumulate column sums of the result into g_mean (mix2 epilogue).
// ---------------------------------------------------------------------------
template<int NN, int EPIM, bool DUAL, bool MEAN>
__device__ __forceinline__ void gemm_bf16_dev(
    const ushort_t* __restrict__ Abf, const ushort_t* __restrict__ Wbf,
    const float* __restrict__ bias, const float* __restrict__ res,
    float* __restrict__ out, ushort_t* __restrict__ obf) {
  __shared__ ushort_t As[64][72];
  __shared__ ushort_t Bs[64][72];
  constexpr int NB = NN / 64;
  const int tid  = threadIdx.x;
  const int m0   = (blockIdx.x / NB) * 64;
  const int n0   = (blockIdx.x % NB) * 64;
  const int lane = tid & 63;
  const int wv   = tid >> 6;
  const int quad = lane >> 4;
  const int ln   = lane & 15;
  const int mw   = (wv & 1) * 32;
  const int nw   = (wv >> 1) * 32;

  f4_t acc[2][2] = {};

  for (int k0 = 0; k0 < 512; k0 += 64) {
#pragma unroll
    for (int c = 0; c < 2; ++c) {
      int idx = tid + c * 256;                 // 512 chunks of 8 bf16
      int m = idx >> 3, kq = (idx & 7) << 3;
      *(float4*)&As[m][kq] = *(const float4*)&Abf[(size_t)(m0 + m) * 512 + k0 + kq];
      *(float4*)&Bs[m][kq] = *(const float4*)&Wbf[(size_t)(n0 + m) * 512 + k0 + kq];
    }
    __syncthreads();
#pragma unroll
    for (int k1 = 0; k1 < 64; k1 += 32) {
      bf8_t a0 = *(const bf8_t*)&As[mw +      ln][k1 + quad * 8];
      bf8_t a1 = *(const bf8_t*)&As[mw + 16 + ln][k1 + quad * 8];
      bf8_t b0 = *(const bf8_t*)&Bs[nw +      ln][k1 + quad * 8];
      bf8_t b1 = *(const bf8_t*)&Bs[nw + 16 + ln][k1 + quad * 8];
      acc[0][0] = __builtin_amdgcn_mfma_f32_16x16x32_bf16(a0, b0, acc[0][0], 0, 0, 0);
      acc[0][1] = __builtin_amdgcn_mfma_f32_16x16x32_bf16(a0, b1, acc[0][1], 0, 0, 0);
      acc[1][0] = __builtin_amdgcn_mfma_f32_16x16x32_bf16(a1, b0, acc[1][0], 0, 0, 0);
      acc[1][1] = __builtin_amdgcn_mfma_f32_16x16x32_bf16(a1, b1, acc[1][1], 0, 0, 0);
    }
    __syncthreads();
  }

  float bj[2] = {0.f, 0.f};
  if constexpr (EPIM == 1) {
    bj[0] = bias[n0 + nw + ln];
    bj[1] = bias[n0 + nw + 16 + ln];
  }
  float psum[2][2] = {{0.f, 0.f}, {0.f, 0.f}};
#pragma unroll
  for (int i = 0; i < 2; ++i)
#pragma unroll
    for (int j = 0; j < 2; ++j) {
      const int nc = n0 + nw + 16 * j + ln;
#pragma unroll
      for (int r = 0; r < 4; ++r) {
        const int row = m0 + mw + 16 * i + quad * 4 + r;
        const size_t idx = (size_t)row * NN + nc;
        float v = acc[i][j][r];
        if constexpr (EPIM == 1) v += bj[j] + res[idx];
        out[idx] = v;
        if constexpr (DUAL) obf[idx] = f2bf(v);
        if constexpr (MEAN) psum[i][j] += v;
      }
    }
  if constexpr (MEAN) {
    __shared__ float ssum[16][64];
#pragma unroll
    for (int i = 0; i < 2; ++i)
#pragma unroll
      for (int j = 0; j < 2; ++j) {
        const int rg = (wv & 1) * 8 + i * 4 + quad;        // 16 row-groups
        const int cl = (wv >> 1) * 32 + j * 16 + ln;       // 64 cols
        ssum[rg][cl] = psum[i][j];
      }
    __syncthreads();
    if (tid < 64) {
      float s = 0.f;
#pragma unroll
      for (int rg = 0; rg < 16; ++rg) s += ssum[rg][tid];
      const int b = m0 >> 10;                              // m-tile within one batch
      atomicAdd(&g_mean[b * D_ + n0 + tid], s);
    }
  }
}

// Wrappers binding device globals in device code.
__global__ __launch_bounds__(256) void k_xdbl1g() {
  gemm_bf16_dev<64, 0, false, false>(g_hbf, g_xp1bf, nullptr, nullptr, g_xdbl, nullptr);
}
__global__ __launch_bounds__(256) void k_xdbl2g() {
  gemm_bf16_dev<64, 0, false, false>(g_hbf, g_xp2bf, nullptr, nullptr, g_xdbl, nullptr);
}
__global__ __launch_bounds__(256) void k_mix1g(const float* __restrict__ bias) {
  gemm_bf16_dev<512, 1, true, false>(g_gelubf, g_w1bf, bias, g_h, g_h2, g_hbf);
}
__global__ __launch_bounds__(256) void k_mix2g(const float* __restrict__ bias) {
  gemm_bf16_dev<512, 1, false, true>(g_gelubf, g_w2bf, bias, g_h2, g_h, nullptr);
}

// ---------------------------------------------------------------------------
// In-projection as bf16 MFMA with inline fp32->bf16 conversion at staging.
// out h[m,d] = sum_i x[m,i] * W_in[d,i]  + b;  K=64 (one staging round).
// ---------------------------------------------------------------------------
__global__ __launch_bounds__(256) void k_in_mfma(const float* __restrict__ x,
                                                 const float* __restrict__ w,
                                                 const float* __restrict__ bias) {
  __shared__ ushort_t As[64][72];
  __shared__ ushort_t Bs[64][72];
  const int tid  = threadIdx.x;
  const int m0   = (blockIdx.x >> 3) * 64;     // D_/64 = 8 n-tiles
  const int n0   = (blockIdx.x & 7) * 64;
  const int lane = tid & 63;
  const int wv   = tid >> 6;
  const int quad = lane >> 4;
  const int ln   = lane & 15;
  const int mw   = (wv & 1) * 32;
  const int nw   = (wv >> 1) * 32;

  {
    const int m = tid >> 2, q = (tid & 3) << 4;   // row, col-base (16 cols)
#pragma unroll
    for (int i = 0; i < 4; ++i) {
      float4 va = *(const float4*)&x[(size_t)(m0 + m) * 64 + q + i * 4];
      float4 vb = *(const float4*)&w[(size_t)(n0 + m) * 64 + q + i * 4];
      ushort4 oa, ob;
      oa.x = f2bf(va.x); oa.y = f2bf(va.y); oa.z = f2bf(va.z); oa.w = f2bf(va.w);
      ob.x = f2bf(vb.x); ob.y = f2bf(vb.y); ob.z = f2bf(vb.z); ob.w = f2bf(vb.w);
      *(ushort4*)&As[m][q + i * 4] = oa;
      *(ushort4*)&Bs[m][q + i * 4] = ob;
    }
  }
  __syncthreads();

  f4_t acc[2][2] = {};
#pragma unroll
  for (int k1 = 0; k1 < 64; k1 += 32) {
    bf8_t a0 = *(const bf8_t*)&As[mw +      ln][k1 + quad * 8];
    bf8_t a1 = *(const bf8_t*)&As[mw + 16 + ln][k1 + quad * 8];
    bf8_t b0 = *(const bf8_t*)&Bs[nw +      ln][k1 + quad * 8];
    bf8_t b1 = *(const bf8_t*)&Bs[nw + 16 + ln][k1 + quad * 8];
    acc[0][0] = __builtin_amdgcn_mfma_f32_16x16x32_bf16(a0, b0, acc[0][0], 0, 0, 0);
    acc[0][1] = __builtin_amdgcn_mfma_f32_16x16x32_bf16(a0, b1, acc[0][1], 0, 0, 0);
    acc[1][0] = __builtin_amdgcn_mfma_f32_16x16x32_bf16(a1, b0, acc[1][0], 0, 0, 0);
    acc[1][1] = __builtin_amdgcn_mfma_f32_16x16x32_bf16(a1, b1, acc[1][1], 0, 0, 0);
  }

  float bj[2] = { bias[n0 + nw + ln], bias[n0 + nw + 16 + ln] };
#pragma unroll
  for (int i = 0; i < 2; ++i)
#pragma unroll
    for (int j = 0; j < 2; ++j) {
      const int nc = n0 + nw + 16 * j + ln;
#pragma unroll
      for (int r = 0; r < 4; ++r) {
        const int row = m0 + mw + 16 * i + quad * 4 + r;
        const size_t idx = (size_t)row * D_ + nc;
        float v = acc[i][j][r] + bj[j];
        g_h[idx] = v;
        g_hbf[idx] = f2bf(v);
      }
    }
}

// ---------------------------------------------------------------------------
// Fused delta-projection + scan phase 1.  Grid (b,c) = 256 blocks x 512 thr.
// Thread d: delta[l][d] = softplus(dot32(dt[l,:], dtw[d,:]) + dtb[d]) in fp32,
// writes (delta, delta*h) to g_dc, runs the 16-step local scan from 0.
// ---------------------------------------------------------------------------
__device__ __forceinline__ void load_A(const float* __restrict__ Alog, int d,
                                       float* A) {
#pragma unroll
  for (int n = 0; n < 16; n += 4) {
    float4 t = *(const float4*)&Alog[d * N_ + n];
    A[n + 0] = -__expf(t.x); A[n + 1] = -__expf(t.y);
    A[n + 2] = -__expf(t.z); A[n + 3] = -__expf(t.w);
  }
}

__device__ __forceinline__ void dscan_p1_dev(const float* __restrict__ h,
                                             const float* __restrict__ dtw,
                                             const float* __restrict__ dtb,
                                             const float* __restrict__ Alog) {
  __shared__ float sdt[CL_][33];   // dt tile (16 x 32), +1 pad
  __shared__ float sB [CL_][16];
  const int d = threadIdx.x;       // 0..511
  const int c = blockIdx.x & (CN_ - 1);
  const int b = blockIdx.x / CN_;
  const int row0 = b * L_ + c * CL_;

  { int l = d >> 5, k = d & 31; sdt[l][k] = g_xdbl[(size_t)(row0 + l) * RN_ + k]; }
  if (d < CL_ * 16) {
    int l = d >> 4, n = d & 15;
    sB[l][n] = g_xdbl[(size_t)(row0 + l) * RN_ + R_ + n];
  }
  float w[32];
#pragma unroll
  for (int r = 0; r < 32; r += 4) {
    float4 t = *(const float4*)&dtw[d * R_ + r];
    w[r] = t.x; w[r + 1] = t.y; w[r + 2] = t.z; w[r + 3] = t.w;
  }
  const float bias = dtb[d];
  float A[16];
  load_A(Alog, d, A);
  __syncthreads();

  float st[16] = {};
  float sumd = 0.0f;
#pragma unroll
  for (int l = 0; l < CL_; ++l) {
    float acc = bias;
#pragma unroll
    for (int k = 0; k < 32; ++k) acc = fmaf(sdt[l][k], w[k], acc);
    const float delta = softplus_f(acc);
    const float hv = h[(size_t)(row0 + l) * D_ + d];
    const float dh = delta * hv;
    g_dc[(size_t)(row0 + l) * D_ + d] = make_float2(delta, dh);
    sumd += delta;
#pragma unroll
    for (int n = 0; n < 16; ++n) {
      float dA = __expf(delta * A[n]);
      st[n] = fmaf(dA, st[n], dh * sB[l][n]);
    }
  }
  const size_t o = ((size_t)(b * CN_ + c) * D_ + d) * N_;
#pragma unroll
  for (int n = 0; n < 16; n += 4)
    *(float4*)&g_stL[o + n] = make_float4(st[n], st[n+1], st[n+2], st[n+3]);
  g_sumd[(b * CN_ + c) * D_ + d] = sumd;
}

__global__ __launch_bounds__(512) void k_dscan1(const float* dtw, const float* dtb,
                                                const float* Alog) {
  dscan_p1_dev(g_h, dtw, dtb, Alog);
}
__global__ __launch_bounds__(512) void k_dscan2(const float* dtw, const float* dtb,
                                                const float* Alog) {
  dscan_p1_dev(g_h2, dtw, dtb, Alog);
}

// ---------------------------------------------------------------------------
// Carry: H_c = exp(A*sumd_c) * H_{c-1} + S_c, serial over 64 chunks.
// ---------------------------------------------------------------------------
__global__ __launch_bounds__(256) void k_scan_carry(const float* __restrict__ Alog) {
  const int g = blockIdx.x * 256 + threadIdx.x;
  const int n = g & 15;
  const int d = (g >> 4) & (D_ - 1);
  const int b = g >> 13;
  const float A = -__expf(Alog[d * N_ + n]);
  float carry = 0.0f;
#pragma unroll 4
  for (int c = 0; c < CN_; ++c) {
    const size_t idx = ((size_t)(b * CN_ + c) * D_ + d) * N_ + n;
    g_carry[idx] = carry;
    float P = __expf(A * g_sumd[(b * CN_ + c) * D_ + d]);
    carry = fmaf(P, carry, g_stL[idx]);
  }
}

// ---------------------------------------------------------------------------
// Scan phase 2: re-run chunk seeded with carry-in; emit bf16(gelu(y)).
// ---------------------------------------------------------------------------
__device__ __forceinline__ void scan_p2_dev(const float2* __restrict__ dc,
                                            const float*  __restrict__ xdbl,
                                            const float*  __restrict__ h,
                                            const float*  __restrict__ Alog,
                                            const float*  __restrict__ Dp,
                                            ushort_t* __restrict__ ybf) {
  __shared__ float sBC[CL_][32];
  const int d = threadIdx.x;
  const int c = blockIdx.x & (CN_ - 1);
  const int b = blockIdx.x / CN_;
  const int row0 = b * L_ + c * CL_;
  {
    int l = threadIdx.x >> 5, idx = threadIdx.x & 31;
    sBC[l][idx] = xdbl[(size_t)(row0 + l) * RN_ + R_ + idx];
  }
  float A[16];
  load_A(Alog, d, A);
  const float Dpv = Dp[d];
  __syncthreads();

  float st[16];
  const size_t o = ((size_t)(b * CN_ + c) * D_ + d) * N_;
#pragma unroll
  for (int n = 0; n < 16; n += 4) {
    float4 t = *(const float4*)&g_carry[o + n];
    st[n] = t.x; st[n+1] = t.y; st[n+2] = t.z; st[n+3] = t.w;
  }
#pragma unroll
  for (int l = 0; l < CL_; ++l) {
    float2 dcv = dc[(size_t)(row0 + l) * D_ + d];
    float y = 0.0f;
#pragma unroll
    for (int n = 0; n < 16; ++n) {
      float dA = __expf(dcv.x * A[n]);
      st[n] = fmaf(dA, st[n], dcv.y * sBC[l][n]);
      y = fmaf(st[n], sBC[l][16 + n], y);
    }
    float hv = h[(size_t)(row0 + l) * D_ + d];
    ybf[(size_t)(row0 + l) * D_ + d] = f2bf(gelu_f(y + hv * Dpv));
  }
}

__global__ __launch_bounds__(512) void k_scan1_p2(const float* Alog, const float* Dp) {
  scan_p2_dev(g_dc, g_xdbl, g_h, Alog, Dp, g_gelubf);
}
__global__ __launch_bounds__(512) void k_scan2_p2(const float* Alog, const float* Dp) {
  scan_p2_dev(g_dc, g_xdbl, g_h2, Alog, Dp, g_gelubf);
}

// ---------------------------------------------------------------------------
// Head: mean (pre-accumulated column sums in g_mean) + out-proj.
// ---------------------------------------------------------------------------
__global__ __launch_bounds__(512) void k_finalB(const float* out_w, const float* out_b,
                                                float* out) {
  __shared__ float sm[D_];
  __shared__ float sp[DOUT_ * 16];
  const int b = blockIdx.x, tid = threadIdx.x;
  sm[tid] = g_mean[b * D_ + tid] * (1.0f / L_);
  __syncthreads();
  if (tid < DOUT_ * 16) {
    int o = tid >> 4, seg = tid & 15;
    float p = 0.0f;
#pragma unroll
    for (int i = 0; i < 32; ++i)
      p += sm[seg * 32 + i] * out_w[o * D_ + seg * 32 + i];
    sp[tid] = p;
  }
  __syncthreads();
  if (tid < DOUT_) {
    float v = out_b[tid];
#pragma unroll
    for (int i = 0; i < 16; ++i) v += sp[tid * 16 + i];
    out[b * DOUT_ + tid] = v;
  }
}

extern "C" void kernel_launch(void* const* d_in, const int* in_sizes, int n_in,
                              void* d_out, int out_size, void* d_ws, size_t ws_size,
                              hipStream_t stream) {
  const float* x        = (const float*)d_in[0];
  const float* W_in     = (const float*)d_in[1];
  const float* b_in     = (const float*)d_in[2];
  const float* mix1_w   = (const float*)d_in[3];
  const float* mix1_b   = (const float*)d_in[4];
  const float* mix2_w   = (const float*)d_in[5];
  const float* mix2_b   = (const float*)d_in[6];
  const float* out_w    = (const float*)d_in[7];
  const float* out_b    = (const float*)d_in[8];
  const float* m1_xproj = (const float*)d_in[9];
  const float* m1_dtw   = (const float*)d_in[10];
  const float* m1_dtb   = (const float*)d_in[11];
  const float* m1_Alog  = (const float*)d_in[12];
  const float* m1_D     = (const float*)d_in[13];
  const float* m2_xproj = (const float*)d_in[14];
  const float* m2_dtw   = (const float*)d_in[15];
  const float* m2_dtb   = (const float*)d_in[16];
  const float* m2_Alog  = (const float*)d_in[17];
  const float* m2_D     = (const float*)d_in[18];
  float* out = (float*)d_out;

  const int gScan  = B_ * CN_;                // 256
  const int gCarry = (B_ * D_ * N_) / 256;    // 128
  const int gMix   = (M_ / 64) * (D_ / 64);   // 512
  const int gXdbl  = (M_ / 64);               // 64

  k_cvt    <<<577,  256, 0, stream>>>(mix1_w, mix2_w, m1_xproj, m2_xproj);
  k_in_mfma<<<gMix, 256, 0, stream>>>(x, W_in, b_in);

  // ---- layer 1 ----
  k_xdbl1g  <<<gXdbl, 256, 0, stream>>>();
  k_dscan1  <<<gScan, 512, 0, stream>>>(m1_dtw, m1_dtb, m1_Alog);
  k_scan_carry<<<gCarry, 256, 0, stream>>>(m1_Alog);
  k_scan1_p2<<<gScan, 512, 0, stream>>>(m1_Alog, m1_D);
  k_mix1g   <<<gMix,  256, 0, stream>>>(mix1_b);
  // ---- layer 2 ----
  k_xdbl2g  <<<gXdbl, 256, 0, stream>>>();
  k_dscan2  <<<gScan, 512, 0, stream>>>(m2_dtw, m2_dtb, m2_Alog);
  k_scan_carry<<<gCarry, 256, 0, stream>>>(m2_Alog);
  k_scan2_p2<<<gScan, 512, 0, stream>>>(m2_Alog, m2_D);
  k_mix2g   <<<gMix,  256, 0, stream>>>(mix2_b);
  // ---- head ----
  k_finalB<<<B_, 512, 0, stream>>>(out_w, out_b, out);
}